// Round 1
// baseline (5212.573 us; speedup 1.0000x reference)
//
#include <hip/hip_runtime.h>
#include <hip/hip_bf16.h>

// Problem constants
#define BATCH 32
#define TLEN 512
#define INCH 512
#define HID 512

typedef __bf16 bf16x8 __attribute__((ext_vector_type(8)));
typedef float f32x4 __attribute__((ext_vector_type(4)));
typedef unsigned int u32x4 __attribute__((ext_vector_type(4)));
typedef unsigned short u16x4 __attribute__((ext_vector_type(4)));
using bf16 = __hip_bfloat16;

// ---------------- ws layout (bytes) ----------------
#define OFF_XS2   0ull                      // 16384*512*2 = 16 MiB
#define OFF_WCAT  16777216ull               // 4096*512*2  = 4 MiB
#define OFF_WHHP  20971520ull               // 2*2048*512*2 = 4 MiB
#define OFF_BIAS  25165824ull               // 2*2048*4 = 16 KiB
#define OFF_HBUF  25182208ull               // 2dir*2buf*32*512*2 = 128 KiB
#define OFF_CTR   25313280ull               // 256 B (legacy, unused)
#define OFF_FLAG  25313536ull               // packed per-wave flags, 2*256*4 = 2 KiB used
#define OFF_XP    25321728ull               // 512*2*2048*32*2 = 128 MiB
#define WS_REQUIRED (25321728ull + 134217728ull)

__device__ __forceinline__ float sigmoid_fast(float x) {
    return 1.f / (1.f + __expf(-x));
}
__device__ __forceinline__ float tanh_fast(float x) {
    float ax = fabsf(x);
    float e = __expf(-2.f * ax);
    float r = (1.f - e) / (1.f + e);
    return copysignf(r, x);
}
__device__ __forceinline__ float bf2f(unsigned short u) {
    unsigned int i = ((unsigned int)u) << 16;
    float f; __builtin_memcpy(&f, &i, 4); return f;
}

__global__ void ws_too_small_kernel(float* out) {
    if (threadIdx.x == 0 && blockIdx.x == 0) out[0] = 12345.0f;
}

// ---------------- pack x -> XS2[(t*32+b)][k] bf16 ----------------
__global__ void pack_x_kernel(const float* __restrict__ x, bf16* __restrict__ XS2) {
    int bx = blockIdx.x;               // 2048 blocks
    int b  = bx >> 6;
    int tt = (bx >> 3) & 7;
    int kt = bx & 7;
    __shared__ float tile[64][65];
    int tid  = threadIdx.x;
    int row2 = tid >> 6;
    int col  = tid & 63;
#pragma unroll
    for (int i = 0; i < 16; ++i) {
        int row = i * 4 + row2;
        int k = kt * 64 + row;
        tile[row][col] = x[((b * 32 + (k >> 4)) * 16 + (k & 15)) * 512 + tt * 64 + col];
    }
    __syncthreads();
#pragma unroll
    for (int i = 0; i < 16; ++i) {
        int trow = i * 4 + row2;
        int t = tt * 64 + trow;
        XS2[(t * 32 + b) * 512 + kt * 64 + col] = __float2bfloat16(tile[col][trow]);
    }
}

// ---------------- pack weights / bias / zero-init ----------------
// Whhp row permutation: local row lm (0..63 per s) = ul*4 + gate, i.e.
// grow = gate*512 + s*16 + ul with gate = lm&3, ul = lm>>2.  With the MFMA
// C-layout row = fq*4+rr this puts all 4 gates of one cell into one lane's acc.
// bias repacked to [dir][s][ul][gate] f32 (float4 per cell).
__global__ void pack_w_kernel(const float* __restrict__ Wih_f, const float* __restrict__ Whh_f,
                              const float* __restrict__ bih_f, const float* __restrict__ bhh_f,
                              const float* __restrict__ Wih_b, const float* __restrict__ Whh_b,
                              const float* __restrict__ bih_b, const float* __restrict__ bhh_b,
                              bf16* __restrict__ Wcat, bf16* __restrict__ Whhp,
                              float* __restrict__ bias, unsigned int* __restrict__ hbuf32,
                              unsigned int* __restrict__ ctr, unsigned int* __restrict__ flags) {
    long idx = (long)blockIdx.x * 256 + threadIdx.x;
    if (idx < 262144) {                       // Wcat, 8-wide
        long e = idx * 8;
        int m = (int)(e >> 9), k = (int)(e & 511);
        const float* src = (m < 2048) ? &Wih_f[(long)m * 512 + k]
                                      : &Wih_b[(long)(m - 2048) * 512 + k];
        bf16* dst = &Wcat[e];
#pragma unroll
        for (int j = 0; j < 8; ++j) dst[j] = __float2bfloat16(src[j]);
        return;
    }
    idx -= 262144;
    if (idx < 262144) {                       // Whhp, 8-wide (gate-interleaved rows)
        long e = idx * 8;
        int k  = (int)(e & 511);
        int lm = (int)((e >> 9) & 63);
        int s  = (int)((e >> 15) & 31);
        int dir = (int)(e >> 20);
        int grow = (lm & 3) * 512 + s * 16 + (lm >> 2);
        const float* W = dir ? Whh_b : Whh_f;
        const float* src = &W[(long)grow * 512 + k];
        bf16* dst = &Whhp[e];
#pragma unroll
        for (int j = 0; j < 8; ++j) dst[j] = __float2bfloat16(src[j]);
        return;
    }
    idx -= 262144;
    if (idx < 4096) {                         // bias = b_ih + b_hh, [dir][s][ul][gate]
        int dir  = (int)(idx >> 11);
        int r    = (int)(idx & 2047);
        int s    = r >> 6, ul = (r >> 2) & 15, gate = r & 3;
        int g    = gate * 512 + s * 16 + ul;
        bias[idx] = (dir ? (bih_b[g] + bhh_b[g]) : (bih_f[g] + bhh_f[g]));
        return;
    }
    idx -= 4096;
    if (idx < 32768) { hbuf32[idx] = 0u; return; }  // zero h ping-pong
    idx -= 32768;
    if (idx < 64) { ctr[idx] = 0u; return; }
    idx -= 64;
    if (idx < 2048) { flags[idx] = 0u; return; }    // zero epoch flags
}

// ---------------- phase 1: XP = Wcat * XS2^T ----------------
// XP[t][dir][s][ul][b][gate] bf16  -> each lstm lane loads its 4 gates as one 8B chunk
__global__ __launch_bounds__(256, 2) void gemm_xp_kernel(const bf16* __restrict__ Wcat,
                                                         const bf16* __restrict__ XS2,
                                                         bf16* __restrict__ XP) {
    int bm = (blockIdx.x & 31) * 128;
    int bn = (blockIdx.x >> 5) * 128;
    __shared__ bf16 lA[128 * 40];
    __shared__ bf16 lB[128 * 40];
    int tid = threadIdx.x;
    int lane = tid & 63, w = tid >> 6;
    int wm = (w & 1) * 64, wn = (w >> 1) * 64;
    int fr = lane & 15, fq = lane >> 4;
    f32x4 acc[4][4] = {};
    int r = tid >> 2, c = tid & 3;
    for (int kt = 0; kt < 16; ++kt) {
        int k0 = kt * 32;
        *(bf16x8*)&lA[r * 40 + c * 8]        = *(const bf16x8*)&Wcat[(long)(bm + r) * 512 + k0 + c * 8];
        *(bf16x8*)&lA[(r + 64) * 40 + c * 8] = *(const bf16x8*)&Wcat[(long)(bm + r + 64) * 512 + k0 + c * 8];
        *(bf16x8*)&lB[r * 40 + c * 8]        = *(const bf16x8*)&XS2[(long)(bn + r) * 512 + k0 + c * 8];
        *(bf16x8*)&lB[(r + 64) * 40 + c * 8] = *(const bf16x8*)&XS2[(long)(bn + r + 64) * 512 + k0 + c * 8];
        __syncthreads();
        bf16x8 af[4], bfm[4];
#pragma unroll
        for (int i = 0; i < 4; ++i) af[i]  = *(const bf16x8*)&lA[(wm + i * 16 + fr) * 40 + fq * 8];
#pragma unroll
        for (int i = 0; i < 4; ++i) bfm[i] = *(const bf16x8*)&lB[(wn + i * 16 + fr) * 40 + fq * 8];
#pragma unroll
        for (int mi = 0; mi < 4; ++mi)
#pragma unroll
            for (int ni = 0; ni < 4; ++ni)
                acc[mi][ni] = __builtin_amdgcn_mfma_f32_16x16x32_bf16(af[mi], bfm[ni], acc[mi][ni], 0, 0, 0);
        __syncthreads();
    }
#pragma unroll
    for (int mi = 0; mi < 4; ++mi) {
#pragma unroll
        for (int rr = 0; rr < 4; ++rr) {
            int m = bm + wm + mi * 16 + fq * 4 + rr;
            int dir = m >> 11, cc = m & 2047;
            int gate = cc >> 9, u = cc & 511, s = u >> 4, ul = u & 15;
#pragma unroll
            for (int ni = 0; ni < 4; ++ni) {
                int n = bn + wn + ni * 16 + fr;
                int t = n >> 5, b = n & 31;
                long off = ((long)(t * 2 + dir) * 32 + s) * 2048 + (long)(ul * 32 + b) * 4 + gate;
                XP[off] = __float2bfloat16(acc[mi][ni][rr]);
            }
        }
    }
}

// ---------------- phase 2: bidirectional LSTM recurrence ----------------
// 64 blocks (dir, s) x 512 threads = 8 waves, each wave fully autonomous:
// NO __syncthreads in the 512-step loop.  Per lane: one cell (ul,b), all 4
// gates land in acc[0..3] (gate-interleaved Whhp).  h exchanged via
// device-coherent sc0/sc1 accesses; per-wave epoch flags packed into 1 KiB
// per direction (8 cache lines) polled with a single dwordx4 per lane.
__global__ __launch_bounds__(512, 2) void lstm_rec_kernel(const bf16* __restrict__ Whhp,
                                                          const bf16* __restrict__ XP,
                                                          const float* __restrict__ bias,
                                                          bf16* hbuf, float* out,
                                                          unsigned int* flags) {
    int bx = blockIdx.x;
    int dir = bx >> 5, s = bx & 31;
    int tid = threadIdx.x;
    int lane = tid & 63, w = tid >> 6;      // 8 waves
    int mt = w & 3, nt = w >> 2;            // wave -> (ul-quad, batch half)
    int fr = lane & 15, fq = lane >> 4;
    __shared__ float obuf[16][512];         // 32 KiB output chunk (per-thread column)

    // persistent A fragments: Whhp[dir][s][mt*16+fr][k] (rows are gate-interleaved)
    const bf16* wbase = Whhp + ((long)((dir * 32 + s) * 64 + mt * 16 + fr)) * 512 + fq * 8;
    bf16x8 wA[16];
#pragma unroll
    for (int kt = 0; kt < 16; ++kt) wA[kt] = *(const bf16x8*)(wbase + kt * 32);

    int ul = mt * 4 + fq;                   // hidden sub-index within s
    int b  = nt * 16 + fr;                  // batch
    f32x4 bv = *(const f32x4*)&bias[((dir * 32 + s) * 16 + ul) * 4];
    float cstate = 0.f;

    bf16* hb_dir = hbuf + (long)dir * 2 * BATCH * HID;
    unsigned int* myflag = flags + dir * 256 + s * 8 + w;
    const unsigned int* pollptr = flags + dir * 256 + lane * 4;
    bf16* hstore_base = hb_dir + (long)b * HID + s * 16 + ul;
    const bf16* hload_base = hb_dir + (long)b * HID + fq * 8;
    float* outrow = out + (long)b * 524288 + (long)(dir * 512 + s * 16 + ul) * 512;
    int guard = 1 << 21;

    for (int t = 0; t < TLEN; ++t) {
        int ttime = dir ? (TLEN - 1 - t) : t;
        // xp prefetch (normal cached load): 4 gates of this cell, 8 bytes
        const bf16* xpp = XP + (long)(ttime * 2 + dir) * 65536 + s * 2048 + (ul * 32 + b) * 4;
        u16x4 xv = *(const u16x4*)xpp;

        if (t > 0) {
            // poll all 256 peer-wave flags of this direction (8 lines total)
            unsigned int tt = (unsigned int)t;
            for (;;) {
                u32x4 fv;
                asm volatile("global_load_dwordx4 %0, %1, off sc0 sc1\n\t"
                             "s_waitcnt vmcnt(0)"
                             : "=&v"(fv) : "v"(pollptr) : "memory");
                int ok = (fv.x >= tt) & (fv.y >= tt) & (fv.z >= tt) & (fv.w >= tt);
                if (__all(ok)) break;
                if (--guard <= 0) break;
            }
        }

        // B fragments straight from the coherent h buffer: 16 x dwordx4,
        // one base address + offset: immediates (row b, k = kt*32 + fq*8)
        const bf16* hsrc = hload_base + (long)(t & 1) * (BATCH * HID);
        bf16x8 hB[16];
        asm volatile(
            "global_load_dwordx4 %0, %8, off sc0 sc1\n\t"
            "global_load_dwordx4 %1, %8, off offset:64 sc0 sc1\n\t"
            "global_load_dwordx4 %2, %8, off offset:128 sc0 sc1\n\t"
            "global_load_dwordx4 %3, %8, off offset:192 sc0 sc1\n\t"
            "global_load_dwordx4 %4, %8, off offset:256 sc0 sc1\n\t"
            "global_load_dwordx4 %5, %8, off offset:320 sc0 sc1\n\t"
            "global_load_dwordx4 %6, %8, off offset:384 sc0 sc1\n\t"
            "global_load_dwordx4 %7, %8, off offset:448 sc0 sc1"
            : "=&v"(hB[0]), "=&v"(hB[1]), "=&v"(hB[2]), "=&v"(hB[3]),
              "=&v"(hB[4]), "=&v"(hB[5]), "=&v"(hB[6]), "=&v"(hB[7])
            : "v"(hsrc) : "memory");
        asm volatile(
            "global_load_dwordx4 %0, %8, off offset:512 sc0 sc1\n\t"
            "global_load_dwordx4 %1, %8, off offset:576 sc0 sc1\n\t"
            "global_load_dwordx4 %2, %8, off offset:640 sc0 sc1\n\t"
            "global_load_dwordx4 %3, %8, off offset:704 sc0 sc1\n\t"
            "global_load_dwordx4 %4, %8, off offset:768 sc0 sc1\n\t"
            "global_load_dwordx4 %5, %8, off offset:832 sc0 sc1\n\t"
            "global_load_dwordx4 %6, %8, off offset:896 sc0 sc1\n\t"
            "global_load_dwordx4 %7, %8, off offset:960 sc0 sc1\n\t"
            "s_waitcnt vmcnt(0)"
            : "=&v"(hB[8]), "=&v"(hB[9]), "=&v"(hB[10]), "=&v"(hB[11]),
              "=&v"(hB[12]), "=&v"(hB[13]), "=&v"(hB[14]), "=&v"(hB[15])
            : "v"(hsrc) : "memory");
        __builtin_amdgcn_sched_barrier(0);   // keep MFMAs after the vmcnt(0)

        // two interleaved accumulation chains over K=512
        f32x4 a0 = {}, a1 = {};
#pragma unroll
        for (int kt = 0; kt < 16; kt += 2) {
            a0 = __builtin_amdgcn_mfma_f32_16x16x32_bf16(wA[kt],     hB[kt],     a0, 0, 0, 0);
            a1 = __builtin_amdgcn_mfma_f32_16x16x32_bf16(wA[kt + 1], hB[kt + 1], a1, 0, 0, 0);
        }

        // gates fully in-register: acc[rr] = gate rr of this lane's cell
        float gi = a0[0] + a1[0] + bv[0] + bf2f(xv.x);
        float gf = a0[1] + a1[1] + bv[1] + bf2f(xv.y);
        float gg = a0[2] + a1[2] + bv[2] + bf2f(xv.z);
        float go = a0[3] + a1[3] + bv[3] + bf2f(xv.w);
        float si = sigmoid_fast(gi), sf = sigmoid_fast(gf), so = sigmoid_fast(go);
        cstate = sf * cstate + si * tanh_fast(gg);
        float h = so * tanh_fast(cstate);

        // device-coherent 2B h store -> drain -> lane-0 posts this wave's flag
        bf16 hb16 = __float2bfloat16(h);
        unsigned short hsb; __builtin_memcpy(&hsb, &hb16, 2);
        unsigned int hreg = hsb;
        bf16* haddr = hstore_base + (long)((t + 1) & 1) * (BATCH * HID);
        asm volatile("global_store_short %0, %1, off sc0 sc1"
                     :: "v"(haddr), "v"(hreg) : "memory");
        asm volatile("s_waitcnt vmcnt(0)" ::: "memory");
        if (lane == 0)
            __hip_atomic_store(myflag, (unsigned int)(t + 1), __ATOMIC_RELAXED,
                               __HIP_MEMORY_SCOPE_AGENT);

        // output buffering: each thread owns its obuf column, no barrier needed
        obuf[ttime & 15][tid] = h;
        if ((t & 15) == 15) {
            int tb = ttime & ~15;
            float vals[16];
#pragma unroll
            for (int c = 0; c < 16; ++c) vals[c] = obuf[c][tid];
            float* op = outrow + tb;
#pragma unroll
            for (int c4 = 0; c4 < 4; ++c4)
                *(f32x4*)(op + c4 * 4) = *(f32x4*)&vals[c4 * 4];
        }
    }
}

extern "C" void kernel_launch(void* const* d_in, const int* in_sizes, int n_in,
                              void* d_out, int out_size, void* d_ws, size_t ws_size,
                              hipStream_t stream) {
    const float* x     = (const float*)d_in[0];
    const float* Wih_f = (const float*)d_in[1];
    const float* Whh_f = (const float*)d_in[2];
    const float* bih_f = (const float*)d_in[3];
    const float* bhh_f = (const float*)d_in[4];
    const float* Wih_b = (const float*)d_in[5];
    const float* Whh_b = (const float*)d_in[6];
    const float* bih_b = (const float*)d_in[7];
    const float* bhh_b = (const float*)d_in[8];
    float* out = (float*)d_out;

    if (ws_size < WS_REQUIRED) {
        ws_too_small_kernel<<<1, 64, 0, stream>>>(out);
        return;
    }

    char* ws = (char*)d_ws;
    bf16* XS2  = (bf16*)(ws + OFF_XS2);
    bf16* Wcat = (bf16*)(ws + OFF_WCAT);
    bf16* Whhp = (bf16*)(ws + OFF_WHHP);
    float* bias = (float*)(ws + OFF_BIAS);
    bf16* hbuf = (bf16*)(ws + OFF_HBUF);
    unsigned int* ctr   = (unsigned int*)(ws + OFF_CTR);
    unsigned int* flags = (unsigned int*)(ws + OFF_FLAG);
    bf16* XP   = (bf16*)(ws + OFF_XP);

    pack_x_kernel<<<2048, 256, 0, stream>>>(x, XS2);
    pack_w_kernel<<<2201, 256, 0, stream>>>(Wih_f, Whh_f, bih_f, bhh_f,
                                            Wih_b, Whh_b, bih_b, bhh_b,
                                            Wcat, Whhp, bias, (unsigned int*)hbuf, ctr, flags);
    gemm_xp_kernel<<<4096, 256, 0, stream>>>(Wcat, XS2, XP);
    lstm_rec_kernel<<<64, 512, 0, stream>>>(Whhp, XP, bias, hbuf, out, flags);
}

// Round 3
// 2025.633 us; speedup vs baseline: 2.5733x; 2.5733x over previous
//
#include <hip/hip_runtime.h>
#include <hip/hip_bf16.h>

// Problem constants
#define BATCH 32
#define TLEN 512
#define INCH 512
#define HID 512

typedef __bf16 bf16x8 __attribute__((ext_vector_type(8)));
typedef float f32x4 __attribute__((ext_vector_type(4)));
typedef unsigned short u16x4 __attribute__((ext_vector_type(4)));
using bf16 = __hip_bfloat16;

// ---------------- ws layout (bytes) ----------------
#define OFF_XS2   0ull                      // 16384*512*2 = 16 MiB
#define OFF_WCAT  16777216ull               // 4096*512*2  = 4 MiB
#define OFF_WHHP  20971520ull               // 2*2048*512*2 = 4 MiB
#define OFF_BIAS  25165824ull               // 2*2048*4 = 16 KiB
#define OFF_HBUF  25182208ull               // 2dir*2buf*32*512*2 = 128 KiB
#define OFF_CTR   25313280ull               // 256 B (legacy, unused)
#define OFF_FLAG  25313536ull               // 64 flags * 128 B = 8 KiB
#define OFF_XP    25321728ull               // 512*2*2048*32*2 = 128 MiB
#define WS_REQUIRED (25321728ull + 134217728ull)

__device__ __forceinline__ float sigmoid_fast(float x) {
    return 1.f / (1.f + __expf(-x));
}
__device__ __forceinline__ float tanh_fast(float x) {
    float ax = fabsf(x);
    float e = __expf(-2.f * ax);
    float r = (1.f - e) / (1.f + e);
    return copysignf(r, x);
}
__device__ __forceinline__ float bf2f(unsigned short u) {
    unsigned int i = ((unsigned int)u) << 16;
    float f; __builtin_memcpy(&f, &i, 4); return f;
}

__global__ void ws_too_small_kernel(float* out) {
    if (threadIdx.x == 0 && blockIdx.x == 0) out[0] = 12345.0f;
}

// ---------------- pack x -> XS2[(t*32+b)][k] bf16 ----------------
__global__ void pack_x_kernel(const float* __restrict__ x, bf16* __restrict__ XS2) {
    int bx = blockIdx.x;               // 2048 blocks
    int b  = bx >> 6;
    int tt = (bx >> 3) & 7;
    int kt = bx & 7;
    __shared__ float tile[64][65];
    int tid  = threadIdx.x;
    int row2 = tid >> 6;
    int col  = tid & 63;
#pragma unroll
    for (int i = 0; i < 16; ++i) {
        int row = i * 4 + row2;
        int k = kt * 64 + row;
        tile[row][col] = x[((b * 32 + (k >> 4)) * 16 + (k & 15)) * 512 + tt * 64 + col];
    }
    __syncthreads();
#pragma unroll
    for (int i = 0; i < 16; ++i) {
        int trow = i * 4 + row2;
        int t = tt * 64 + trow;
        XS2[(t * 32 + b) * 512 + kt * 64 + col] = __float2bfloat16(tile[col][trow]);
    }
}

// ---------------- pack weights / bias / zero-init ----------------
// Whhp row permutation: local row lm (0..63 per s) = ul*4 + gate:
// grow = gate*512 + s*16 + ul with gate = lm&3, ul = lm>>2.  With the MFMA
// C-layout row = fq*4+rr this puts all 4 gates of one cell into one lane's acc.
// bias repacked to [dir][s][ul][gate] f32 (float4 per cell).
__global__ void pack_w_kernel(const float* __restrict__ Wih_f, const float* __restrict__ Whh_f,
                              const float* __restrict__ bih_f, const float* __restrict__ bhh_f,
                              const float* __restrict__ Wih_b, const float* __restrict__ Whh_b,
                              const float* __restrict__ bih_b, const float* __restrict__ bhh_b,
                              bf16* __restrict__ Wcat, bf16* __restrict__ Whhp,
                              float* __restrict__ bias, unsigned int* __restrict__ hbuf32,
                              unsigned int* __restrict__ ctr, unsigned int* __restrict__ flags) {
    long idx = (long)blockIdx.x * 256 + threadIdx.x;
    if (idx < 262144) {                       // Wcat, 8-wide
        long e = idx * 8;
        int m = (int)(e >> 9), k = (int)(e & 511);
        const float* src = (m < 2048) ? &Wih_f[(long)m * 512 + k]
                                      : &Wih_b[(long)(m - 2048) * 512 + k];
        bf16* dst = &Wcat[e];
#pragma unroll
        for (int j = 0; j < 8; ++j) dst[j] = __float2bfloat16(src[j]);
        return;
    }
    idx -= 262144;
    if (idx < 262144) {                       // Whhp, 8-wide (gate-interleaved rows)
        long e = idx * 8;
        int k  = (int)(e & 511);
        int lm = (int)((e >> 9) & 63);
        int s  = (int)((e >> 15) & 31);
        int dir = (int)(e >> 20);
        int grow = (lm & 3) * 512 + s * 16 + (lm >> 2);
        const float* W = dir ? Whh_b : Whh_f;
        const float* src = &W[(long)grow * 512 + k];
        bf16* dst = &Whhp[e];
#pragma unroll
        for (int j = 0; j < 8; ++j) dst[j] = __float2bfloat16(src[j]);
        return;
    }
    idx -= 262144;
    if (idx < 4096) {                         // bias = b_ih + b_hh, [dir][s][ul][gate]
        int dir  = (int)(idx >> 11);
        int r    = (int)(idx & 2047);
        int s    = r >> 6, ul = (r >> 2) & 15, gate = r & 3;
        int g    = gate * 512 + s * 16 + ul;
        bias[idx] = (dir ? (bih_b[g] + bhh_b[g]) : (bih_f[g] + bhh_f[g]));
        return;
    }
    idx -= 4096;
    if (idx < 32768) { hbuf32[idx] = 0u; return; }  // zero h ping-pong
    idx -= 32768;
    if (idx < 64) { ctr[idx] = 0u; return; }
    idx -= 64;
    if (idx < 2048) { flags[idx] = 0u; return; }    // zero epoch flags
}

// ---------------- phase 1: XP = Wcat * XS2^T ----------------
// XP[t][dir][s][ul][b][gate] bf16 -> each lstm lane loads its 4 gates as one 8B chunk
__global__ __launch_bounds__(256, 2) void gemm_xp_kernel(const bf16* __restrict__ Wcat,
                                                         const bf16* __restrict__ XS2,
                                                         bf16* __restrict__ XP) {
    int bm = (blockIdx.x & 31) * 128;
    int bn = (blockIdx.x >> 5) * 128;
    __shared__ bf16 lA[128 * 40];
    __shared__ bf16 lB[128 * 40];
    int tid = threadIdx.x;
    int lane = tid & 63, w = tid >> 6;
    int wm = (w & 1) * 64, wn = (w >> 1) * 64;
    int fr = lane & 15, fq = lane >> 4;
    f32x4 acc[4][4] = {};
    int r = tid >> 2, c = tid & 3;
    for (int kt = 0; kt < 16; ++kt) {
        int k0 = kt * 32;
        *(bf16x8*)&lA[r * 40 + c * 8]        = *(const bf16x8*)&Wcat[(long)(bm + r) * 512 + k0 + c * 8];
        *(bf16x8*)&lA[(r + 64) * 40 + c * 8] = *(const bf16x8*)&Wcat[(long)(bm + r + 64) * 512 + k0 + c * 8];
        *(bf16x8*)&lB[r * 40 + c * 8]        = *(const bf16x8*)&XS2[(long)(bn + r) * 512 + k0 + c * 8];
        *(bf16x8*)&lB[(r + 64) * 40 + c * 8] = *(const bf16x8*)&XS2[(long)(bn + r + 64) * 512 + k0 + c * 8];
        __syncthreads();
        bf16x8 af[4], bfm[4];
#pragma unroll
        for (int i = 0; i < 4; ++i) af[i]  = *(const bf16x8*)&lA[(wm + i * 16 + fr) * 40 + fq * 8];
#pragma unroll
        for (int i = 0; i < 4; ++i) bfm[i] = *(const bf16x8*)&lB[(wn + i * 16 + fr) * 40 + fq * 8];
#pragma unroll
        for (int mi = 0; mi < 4; ++mi)
#pragma unroll
            for (int ni = 0; ni < 4; ++ni)
                acc[mi][ni] = __builtin_amdgcn_mfma_f32_16x16x32_bf16(af[mi], bfm[ni], acc[mi][ni], 0, 0, 0);
        __syncthreads();
    }
#pragma unroll
    for (int mi = 0; mi < 4; ++mi) {
#pragma unroll
        for (int rr = 0; rr < 4; ++rr) {
            int m = bm + wm + mi * 16 + fq * 4 + rr;
            int dir = m >> 11, cc = m & 2047;
            int gate = cc >> 9, u = cc & 511, s = u >> 4, ul = u & 15;
#pragma unroll
            for (int ni = 0; ni < 4; ++ni) {
                int n = bn + wn + ni * 16 + fr;
                int t = n >> 5, b = n & 31;
                long off = ((long)(t * 2 + dir) * 32 + s) * 2048 + (long)(ul * 32 + b) * 4 + gate;
                XP[off] = __float2bfloat16(acc[mi][ni][rr]);
            }
        }
    }
}

// ---------------- phase 2: bidirectional LSTM recurrence ----------------
// 64 blocks (dir, s) x 512 threads.  Round-0 exchange structure (cooperative
// 32KB LDS staging of h via sc0/sc1 dwordx4, wave-0 coalesced dwordx4 store +
// drain + per-block flag on its own 128B line, relaxed 32-lane poll) combined
// with in-register gate math (gate-interleaved Whhp: no gbuf, TWO barriers
// per step) and 4 interleaved MFMA chains.  Every piece harness-verified in
// rounds 0/1.
__global__ __launch_bounds__(512, 2) void lstm_rec_kernel(const bf16* __restrict__ Whhp,
                                                          const bf16* __restrict__ XP,
                                                          const float* __restrict__ bias,
                                                          bf16* hbuf, float* out,
                                                          unsigned int* flags) {
    int bx = blockIdx.x;
    int dir = bx >> 5, s = bx & 31;
    int tid = threadIdx.x;
    int lane = tid & 63, w = tid >> 6;      // 8 waves
    int mt = w & 3, nt = w >> 2;            // wave -> (ul-quad, batch half)
    int fr = lane & 15, fq = lane >> 4;
    __shared__ float obuf[16][512];         // 32 KiB output chunk (per-thread column)
    __shared__ bf16  hstage[BATCH * 16];    // 1 KiB  h slice [b][ul]
    __shared__ bf16  hsh[32 * 520];         // 32.5 KiB staged h [b][k], pitch 520

    // persistent A fragments: Whhp[dir][s][mt*16+fr][k] (rows gate-interleaved)
    const bf16* wbase = Whhp + ((long)((dir * 32 + s) * 64 + mt * 16 + fr)) * 512 + fq * 8;
    bf16x8 wA[16];
#pragma unroll
    for (int kt = 0; kt < 16; ++kt) wA[kt] = *(const bf16x8*)(wbase + kt * 32);

    int ul = mt * 4 + fq;                   // hidden sub-index within s
    int b  = nt * 16 + fr;                  // batch
    f32x4 bv = *(const f32x4*)&bias[((dir * 32 + s) * 16 + ul) * 4];
    float cstate = 0.f;

    bf16* hb_dir = hbuf + (long)dir * 2 * BATCH * HID;
    unsigned int* myflag = flags + (dir * 32 + s) * 32;               // own 128-B line
    const unsigned int* pollflag = flags + (dir * 32 + (lane & 31)) * 32;
    float* outrow = out + (long)b * 524288 + (long)(dir * 512 + s * 16 + ul) * 512;
    // staging mapping: thread stages 64 B of h: row = tid>>4, cols (tid&15)*32..+32
    int srow = tid >> 4, scol = (tid & 15) * 32;
    int guard = 1 << 21;

    for (int t = 0; t < TLEN; ++t) {
        int ttime = dir ? (TLEN - 1 - t) : t;
        // xp prefetch (normal cached load): 4 gates of this cell, 8 bytes
        const bf16* xpp = XP + (long)(ttime * 2 + dir) * 65536 + s * 2048 + (ul * 32 + b) * 4;
        u16x4 xv = *(const u16x4*)xpp;

        if (t > 0) {
            // every wave polls all 32 peer-block flags (one padded line per lane)
            unsigned int target = (unsigned int)t;
            for (;;) {
                unsigned int v = __hip_atomic_load(pollflag, __ATOMIC_RELAXED,
                                                   __HIP_MEMORY_SCOPE_AGENT);
                if (__all(v >= target)) break;
                if (--guard <= 0) break;
            }
        }

        // stage h (device-coherent 16-B loads, bypass L1/L2) into LDS
        {
            const bf16* src = hb_dir + (long)(t & 1) * BATCH * HID + (long)srow * 512 + scol;
            f32x4 v0, v1, v2, v3;
            asm volatile(
                "global_load_dwordx4 %0, %4, off sc0 sc1\n\t"
                "global_load_dwordx4 %1, %4, off offset:16 sc0 sc1\n\t"
                "global_load_dwordx4 %2, %4, off offset:32 sc0 sc1\n\t"
                "global_load_dwordx4 %3, %4, off offset:48 sc0 sc1\n\t"
                "s_waitcnt vmcnt(0)"
                : "=&v"(v0), "=&v"(v1), "=&v"(v2), "=&v"(v3)
                : "v"(src) : "memory");
            bf16* d = &hsh[srow * 520 + scol];
            *(f32x4*)(d)      = v0;
            *(f32x4*)(d + 8)  = v1;
            *(f32x4*)(d + 16) = v2;
            *(f32x4*)(d + 24) = v3;
        }
        __syncthreads();

        // B fragments from LDS; 4 interleaved MFMA chains over K=512
        f32x4 a0 = {}, a1 = {}, a2 = {}, a3 = {};
        const bf16* hrow = &hsh[(nt * 16 + fr) * 520 + fq * 8];
#pragma unroll
        for (int kt = 0; kt < 16; kt += 4) {
            bf16x8 h0 = *(const bf16x8*)(hrow + (kt + 0) * 32);
            bf16x8 h1 = *(const bf16x8*)(hrow + (kt + 1) * 32);
            bf16x8 h2 = *(const bf16x8*)(hrow + (kt + 2) * 32);
            bf16x8 h3 = *(const bf16x8*)(hrow + (kt + 3) * 32);
            a0 = __builtin_amdgcn_mfma_f32_16x16x32_bf16(wA[kt + 0], h0, a0, 0, 0, 0);
            a1 = __builtin_amdgcn_mfma_f32_16x16x32_bf16(wA[kt + 1], h1, a1, 0, 0, 0);
            a2 = __builtin_amdgcn_mfma_f32_16x16x32_bf16(wA[kt + 2], h2, a2, 0, 0, 0);
            a3 = __builtin_amdgcn_mfma_f32_16x16x32_bf16(wA[kt + 3], h3, a3, 0, 0, 0);
        }

        // gates fully in-register: acc[rr] = gate rr of this lane's cell
        float gi = (a0[0] + a1[0]) + (a2[0] + a3[0]) + bv[0] + bf2f(xv.x);
        float gf = (a0[1] + a1[1]) + (a2[1] + a3[1]) + bv[1] + bf2f(xv.y);
        float gg = (a0[2] + a1[2]) + (a2[2] + a3[2]) + bv[2] + bf2f(xv.z);
        float go = (a0[3] + a1[3]) + (a2[3] + a3[3]) + bv[3] + bf2f(xv.w);
        float si = sigmoid_fast(gi), sf = sigmoid_fast(gf), so = sigmoid_fast(go);
        cstate = sf * cstate + si * tanh_fast(gg);
        float h = so * tanh_fast(cstate);

        hstage[b * 16 + ul] = __float2bfloat16(h);
        obuf[ttime & 15][tid] = h;
        __syncthreads();

        // wave 0: device-coherent h store (64 x 16B) -> drain -> relaxed flag post
        if (w == 0) {
            int hbb = lane >> 1, half = lane & 1;
            f32x4 hv = *(const f32x4*)&hstage[hbb * 16 + half * 8];
            bf16* dst = hb_dir + (long)((t + 1) & 1) * BATCH * HID + (long)hbb * 512
                        + s * 16 + half * 8;
            asm volatile("global_store_dwordx4 %0, %1, off sc0 sc1"
                         :: "v"(dst), "v"(hv) : "memory");
            asm volatile("s_waitcnt vmcnt(0)" ::: "memory");
            if (lane == 0)
                __hip_atomic_store(myflag, (unsigned int)(t + 1), __ATOMIC_RELAXED,
                                   __HIP_MEMORY_SCOPE_AGENT);
        }

        // output flush every 16 steps — after flag post, off the critical path
        if ((t & 15) == 15) {
            int tb = ttime & ~15;
            float vals[16];
#pragma unroll
            for (int c = 0; c < 16; ++c) vals[c] = obuf[c][tid];
            float* op = outrow + tb;
#pragma unroll
            for (int c4 = 0; c4 < 4; ++c4)
                *(f32x4*)(op + c4 * 4) = *(f32x4*)&vals[c4 * 4];
        }
    }
}

extern "C" void kernel_launch(void* const* d_in, const int* in_sizes, int n_in,
                              void* d_out, int out_size, void* d_ws, size_t ws_size,
                              hipStream_t stream) {
    const float* x     = (const float*)d_in[0];
    const float* Wih_f = (const float*)d_in[1];
    const float* Whh_f = (const float*)d_in[2];
    const float* bih_f = (const float*)d_in[3];
    const float* bhh_f = (const float*)d_in[4];
    const float* Wih_b = (const float*)d_in[5];
    const float* Whh_b = (const float*)d_in[6];
    const float* bih_b = (const float*)d_in[7];
    const float* bhh_b = (const float*)d_in[8];
    float* out = (float*)d_out;

    if (ws_size < WS_REQUIRED) {
        ws_too_small_kernel<<<1, 64, 0, stream>>>(out);
        return;
    }

    char* ws = (char*)d_ws;
    bf16* XS2  = (bf16*)(ws + OFF_XS2);
    bf16* Wcat = (bf16*)(ws + OFF_WCAT);
    bf16* Whhp = (bf16*)(ws + OFF_WHHP);
    float* bias = (float*)(ws + OFF_BIAS);
    bf16* hbuf = (bf16*)(ws + OFF_HBUF);
    unsigned int* ctr   = (unsigned int*)(ws + OFF_CTR);
    unsigned int* flags = (unsigned int*)(ws + OFF_FLAG);
    bf16* XP   = (bf16*)(ws + OFF_XP);

    pack_x_kernel<<<2048, 256, 0, stream>>>(x, XS2);
    pack_w_kernel<<<2201, 256, 0, stream>>>(Wih_f, Whh_f, bih_f, bhh_f,
                                            Wih_b, Whh_b, bih_b, bhh_b,
                                            Wcat, Whhp, bias, (unsigned int*)hbuf, ctr, flags);
    gemm_xp_kernel<<<4096, 256, 0, stream>>>(Wcat, XS2, XP);
    lstm_rec_kernel<<<64, 512, 0, stream>>>(Whhp, XP, bias, hbuf, out, flags);
}

// Round 4
// 1957.042 us; speedup vs baseline: 2.6635x; 1.0350x over previous
//
#include <hip/hip_runtime.h>
#include <hip/hip_bf16.h>

// Problem constants
#define BATCH 32
#define TLEN 512
#define INCH 512
#define HID 512

typedef __bf16 bf16x8 __attribute__((ext_vector_type(8)));
typedef float f32x4 __attribute__((ext_vector_type(4)));
typedef unsigned short u16x4 __attribute__((ext_vector_type(4)));
using bf16 = __hip_bfloat16;

// ---------------- ws layout (bytes) ----------------
#define OFF_XS2   0ull                      // 16384*512*2 = 16 MiB
#define OFF_WCAT  16777216ull               // 4096*512*2  = 4 MiB
#define OFF_WHHP  20971520ull               // 2*2048*512*2 = 4 MiB
#define OFF_BIAS  25165824ull               // 2*2048*4 = 16 KiB
#define OFF_HBUF  25182208ull               // 2dir*2buf*32*512*2 = 128 KiB
#define OFF_CTR   25313280ull               // 256 B (legacy, unused)
#define OFF_FLAG  25313536ull               // 64 flags * 128 B = 8 KiB
#define OFF_XP    25321728ull               // 512*2*2048*32*2 = 128 MiB
#define WS_REQUIRED (25321728ull + 134217728ull)

__device__ __forceinline__ float sigmoid_fast(float x) {
    return 1.f / (1.f + __expf(-x));
}
__device__ __forceinline__ float tanh_fast(float x) {
    float ax = fabsf(x);
    float e = __expf(-2.f * ax);
    float r = (1.f - e) / (1.f + e);
    return copysignf(r, x);
}
__device__ __forceinline__ float bf2f(unsigned short u) {
    unsigned int i = ((unsigned int)u) << 16;
    float f; __builtin_memcpy(&f, &i, 4); return f;
}

__global__ void ws_too_small_kernel(float* out) {
    if (threadIdx.x == 0 && blockIdx.x == 0) out[0] = 12345.0f;
}

// ---------------- pack x -> XS2[(t*32+b)][k] bf16 ----------------
__global__ void pack_x_kernel(const float* __restrict__ x, bf16* __restrict__ XS2) {
    int bx = blockIdx.x;               // 2048 blocks
    int b  = bx >> 6;
    int tt = (bx >> 3) & 7;
    int kt = bx & 7;
    __shared__ float tile[64][65];
    int tid  = threadIdx.x;
    int row2 = tid >> 6;
    int col  = tid & 63;
#pragma unroll
    for (int i = 0; i < 16; ++i) {
        int row = i * 4 + row2;
        int k = kt * 64 + row;
        tile[row][col] = x[((b * 32 + (k >> 4)) * 16 + (k & 15)) * 512 + tt * 64 + col];
    }
    __syncthreads();
#pragma unroll
    for (int i = 0; i < 16; ++i) {
        int trow = i * 4 + row2;
        int t = tt * 64 + trow;
        XS2[(t * 32 + b) * 512 + kt * 64 + col] = __float2bfloat16(tile[col][trow]);
    }
}

// ---------------- pack weights / bias / zero-init ----------------
// Whhp row permutation: local row lm (0..63 per s) = ul*4 + gate:
// grow = gate*512 + s*16 + ul with gate = lm&3, ul = lm>>2.  With the MFMA
// C-layout row = fq*4+rr this puts all 4 gates of one cell into one lane's acc.
// bias repacked to [dir][s][ul][gate] f32 (float4 per cell).
__global__ void pack_w_kernel(const float* __restrict__ Wih_f, const float* __restrict__ Whh_f,
                              const float* __restrict__ bih_f, const float* __restrict__ bhh_f,
                              const float* __restrict__ Wih_b, const float* __restrict__ Whh_b,
                              const float* __restrict__ bih_b, const float* __restrict__ bhh_b,
                              bf16* __restrict__ Wcat, bf16* __restrict__ Whhp,
                              float* __restrict__ bias, unsigned int* __restrict__ hbuf32,
                              unsigned int* __restrict__ ctr, unsigned int* __restrict__ flags) {
    long idx = (long)blockIdx.x * 256 + threadIdx.x;
    if (idx < 262144) {                       // Wcat, 8-wide
        long e = idx * 8;
        int m = (int)(e >> 9), k = (int)(e & 511);
        const float* src = (m < 2048) ? &Wih_f[(long)m * 512 + k]
                                      : &Wih_b[(long)(m - 2048) * 512 + k];
        bf16* dst = &Wcat[e];
#pragma unroll
        for (int j = 0; j < 8; ++j) dst[j] = __float2bfloat16(src[j]);
        return;
    }
    idx -= 262144;
    if (idx < 262144) {                       // Whhp, 8-wide (gate-interleaved rows)
        long e = idx * 8;
        int k  = (int)(e & 511);
        int lm = (int)((e >> 9) & 63);
        int s  = (int)((e >> 15) & 31);
        int dir = (int)(e >> 20);
        int grow = (lm & 3) * 512 + s * 16 + (lm >> 2);
        const float* W = dir ? Whh_b : Whh_f;
        const float* src = &W[(long)grow * 512 + k];
        bf16* dst = &Whhp[e];
#pragma unroll
        for (int j = 0; j < 8; ++j) dst[j] = __float2bfloat16(src[j]);
        return;
    }
    idx -= 262144;
    if (idx < 4096) {                         // bias = b_ih + b_hh, [dir][s][ul][gate]
        int dir  = (int)(idx >> 11);
        int r    = (int)(idx & 2047);
        int s    = r >> 6, ul = (r >> 2) & 15, gate = r & 3;
        int g    = gate * 512 + s * 16 + ul;
        bias[idx] = (dir ? (bih_b[g] + bhh_b[g]) : (bih_f[g] + bhh_f[g]));
        return;
    }
    idx -= 4096;
    if (idx < 32768) { hbuf32[idx] = 0u; return; }  // zero h ping-pong
    idx -= 32768;
    if (idx < 64) { ctr[idx] = 0u; return; }
    idx -= 64;
    if (idx < 2048) { flags[idx] = 0u; return; }    // zero epoch flags
}

// ---------------- phase 1: XP = Wcat * XS2^T ----------------
// XP[t][dir][s][ul][b][gate] bf16 -> each lstm lane loads its 4 gates as one 8B chunk
__global__ __launch_bounds__(256, 2) void gemm_xp_kernel(const bf16* __restrict__ Wcat,
                                                         const bf16* __restrict__ XS2,
                                                         bf16* __restrict__ XP) {
    int bm = (blockIdx.x & 31) * 128;
    int bn = (blockIdx.x >> 5) * 128;
    __shared__ bf16 lA[128 * 40];
    __shared__ bf16 lB[128 * 40];
    int tid = threadIdx.x;
    int lane = tid & 63, w = tid >> 6;
    int wm = (w & 1) * 64, wn = (w >> 1) * 64;
    int fr = lane & 15, fq = lane >> 4;
    f32x4 acc[4][4] = {};
    int r = tid >> 2, c = tid & 3;
    for (int kt = 0; kt < 16; ++kt) {
        int k0 = kt * 32;
        *(bf16x8*)&lA[r * 40 + c * 8]        = *(const bf16x8*)&Wcat[(long)(bm + r) * 512 + k0 + c * 8];
        *(bf16x8*)&lA[(r + 64) * 40 + c * 8] = *(const bf16x8*)&Wcat[(long)(bm + r + 64) * 512 + k0 + c * 8];
        *(bf16x8*)&lB[r * 40 + c * 8]        = *(const bf16x8*)&XS2[(long)(bn + r) * 512 + k0 + c * 8];
        *(bf16x8*)&lB[(r + 64) * 40 + c * 8] = *(const bf16x8*)&XS2[(long)(bn + r + 64) * 512 + k0 + c * 8];
        __syncthreads();
        bf16x8 af[4], bfm[4];
#pragma unroll
        for (int i = 0; i < 4; ++i) af[i]  = *(const bf16x8*)&lA[(wm + i * 16 + fr) * 40 + fq * 8];
#pragma unroll
        for (int i = 0; i < 4; ++i) bfm[i] = *(const bf16x8*)&lB[(wn + i * 16 + fr) * 40 + fq * 8];
#pragma unroll
        for (int mi = 0; mi < 4; ++mi)
#pragma unroll
            for (int ni = 0; ni < 4; ++ni)
                acc[mi][ni] = __builtin_amdgcn_mfma_f32_16x16x32_bf16(af[mi], bfm[ni], acc[mi][ni], 0, 0, 0);
        __syncthreads();
    }
#pragma unroll
    for (int mi = 0; mi < 4; ++mi) {
#pragma unroll
        for (int rr = 0; rr < 4; ++rr) {
            int m = bm + wm + mi * 16 + fq * 4 + rr;
            int dir = m >> 11, cc = m & 2047;
            int gate = cc >> 9, u = cc & 511, s = u >> 4, ul = u & 15;
#pragma unroll
            for (int ni = 0; ni < 4; ++ni) {
                int n = bn + wn + ni * 16 + fr;
                int t = n >> 5, b = n & 31;
                long off = ((long)(t * 2 + dir) * 32 + s) * 2048 + (long)(ul * 32 + b) * 4 + gate;
                XP[off] = __float2bfloat16(acc[mi][ni][rr]);
            }
        }
    }
}

// ---------------- phase 2: bidirectional LSTM recurrence ----------------
// 64 blocks (dir, s) x 512 threads.  Changes vs round-3 (verified) kernel:
//  (1) h exchange buffer is block-contiguous: H[buf][dir][s][b][ul] so each
//      block's slice is ONE contiguous 1 KiB chunk -> wave-0 h store is 64
//      coalesced 16B stores to consecutive lines (fast drain), and consumer
//      staging is perfectly coalesced (thread tid loads 64 B at tid*64).
//  (2) only wave 1 polls the 32 peer flags; it bumps an LDS epoch word the
//      other 7 waves spin on locally (8x less IC poll traffic device-wide).
// Everything else (sc0/sc1 h exchange, per-block 128B flag lines, gate-
// interleaved Whhp with in-register gate math, 4 interleaved MFMA chains,
// obuf output batching) is identical to the verified round-3 kernel.
__global__ __launch_bounds__(512, 2) void lstm_rec_kernel(const bf16* __restrict__ Whhp,
                                                          const bf16* __restrict__ XP,
                                                          const float* __restrict__ bias,
                                                          bf16* hbuf, float* out,
                                                          unsigned int* flags) {
    int bx = blockIdx.x;
    int dir = bx >> 5, s = bx & 31;
    int tid = threadIdx.x;
    int lane = tid & 63, w = tid >> 6;      // 8 waves
    int mt = w & 3, nt = w >> 2;            // wave -> (ul-quad, batch half)
    int fr = lane & 15, fq = lane >> 4;
    __shared__ float obuf[16][512];         // 32 KiB output chunk (per-thread column)
    __shared__ bf16  hstage[BATCH * 16];    // 1 KiB  h slice [b][ul]
    __shared__ bf16  hsh[32 * 520];         // 32.5 KiB staged h [b][k], pitch 520
    __shared__ int   eps;                   // LDS epoch broadcast word

    // persistent A fragments: Whhp[dir][s][mt*16+fr][k] (rows gate-interleaved)
    const bf16* wbase = Whhp + ((long)((dir * 32 + s) * 64 + mt * 16 + fr)) * 512 + fq * 8;
    bf16x8 wA[16];
#pragma unroll
    for (int kt = 0; kt < 16; ++kt) wA[kt] = *(const bf16x8*)(wbase + kt * 32);

    int ul = mt * 4 + fq;                   // hidden sub-index within s
    int b  = nt * 16 + fr;                  // batch
    f32x4 bv = *(const f32x4*)&bias[((dir * 32 + s) * 16 + ul) * 4];
    float cstate = 0.f;

    // H[buf][dir][s'][b][ul]: per dir 2 buffers of 16384 elems (32 KiB)
    bf16* hb_dir = hbuf + (long)dir * 2 * 16384;
    unsigned int* myflag = flags + (dir * 32 + s) * 32;               // own 128-B line
    const unsigned int* pollflag = flags + (dir * 32 + (lane & 31)) * 32;
    float* outrow = out + (long)b * 524288 + (long)(dir * 512 + s * 16 + ul) * 512;
    // staging: thread tid loads 4 consecutive 16B chunks at global byte tid*64;
    // chunk c=(4*tid+j) maps to (s'=c>>6, bb=(c>>1)&31, uh=c&1) ->
    // lds elem off = bb*520 + s'*16 + uh*8
    int c0 = tid * 4;
    int sb0 = ((c0 >> 1) & 31) * 520 + (c0 >> 6) * 16;        // chunks 0,1
    int sb1 = (((c0 + 2) >> 1) & 31) * 520 + (c0 >> 6) * 16;  // chunks 2,3
    int guard = 1 << 21;

    if (tid == 0) eps = 0;
    __syncthreads();

    for (int t = 0; t < TLEN; ++t) {
        int ttime = dir ? (TLEN - 1 - t) : t;
        // xp prefetch (normal cached load): 4 gates of this cell, 8 bytes
        const bf16* xpp = XP + (long)(ttime * 2 + dir) * 65536 + s * 2048 + (ul * 32 + b) * 4;
        u16x4 xv = *(const u16x4*)xpp;

        if (t > 0) {
            if (w == 1) {
                // wave 1: poll all 32 peer-block flags (one padded line per lane),
                // then broadcast the epoch via LDS
                unsigned int target = (unsigned int)t;
                for (;;) {
                    unsigned int v = __hip_atomic_load(pollflag, __ATOMIC_RELAXED,
                                                       __HIP_MEMORY_SCOPE_AGENT);
                    if (__all(v >= target)) break;
                    if (--guard <= 0) break;
                }
                if (lane == 0)
                    __hip_atomic_store(&eps, t, __ATOMIC_RELAXED,
                                       __HIP_MEMORY_SCOPE_WORKGROUP);
            } else {
                // other waves: spin on the local LDS epoch word
                while (__hip_atomic_load(&eps, __ATOMIC_RELAXED,
                                         __HIP_MEMORY_SCOPE_WORKGROUP) < t) {
                    if (--guard <= 0) break;
                }
            }
        }

        // stage h (device-coherent, coalesced 64B per thread) into LDS [b][k]
        {
            const bf16* src = hb_dir + (long)(t & 1) * 16384 + (long)tid * 32;
            f32x4 v0, v1, v2, v3;
            asm volatile(
                "global_load_dwordx4 %0, %4, off sc0 sc1\n\t"
                "global_load_dwordx4 %1, %4, off offset:16 sc0 sc1\n\t"
                "global_load_dwordx4 %2, %4, off offset:32 sc0 sc1\n\t"
                "global_load_dwordx4 %3, %4, off offset:48 sc0 sc1\n\t"
                "s_waitcnt vmcnt(0)"
                : "=&v"(v0), "=&v"(v1), "=&v"(v2), "=&v"(v3)
                : "v"(src) : "memory");
            bf16* d0 = &hsh[sb0];
            bf16* d1 = &hsh[sb1];
            *(f32x4*)(d0)     = v0;
            *(f32x4*)(d0 + 8) = v1;
            *(f32x4*)(d1)     = v2;
            *(f32x4*)(d1 + 8) = v3;
        }
        __syncthreads();

        // B fragments from LDS; 4 interleaved MFMA chains over K=512
        f32x4 a0 = {}, a1 = {}, a2 = {}, a3 = {};
        const bf16* hrow = &hsh[(nt * 16 + fr) * 520 + fq * 8];
#pragma unroll
        for (int kt = 0; kt < 16; kt += 4) {
            bf16x8 h0 = *(const bf16x8*)(hrow + (kt + 0) * 32);
            bf16x8 h1 = *(const bf16x8*)(hrow + (kt + 1) * 32);
            bf16x8 h2 = *(const bf16x8*)(hrow + (kt + 2) * 32);
            bf16x8 h3 = *(const bf16x8*)(hrow + (kt + 3) * 32);
            a0 = __builtin_amdgcn_mfma_f32_16x16x32_bf16(wA[kt + 0], h0, a0, 0, 0, 0);
            a1 = __builtin_amdgcn_mfma_f32_16x16x32_bf16(wA[kt + 1], h1, a1, 0, 0, 0);
            a2 = __builtin_amdgcn_mfma_f32_16x16x32_bf16(wA[kt + 2], h2, a2, 0, 0, 0);
            a3 = __builtin_amdgcn_mfma_f32_16x16x32_bf16(wA[kt + 3], h3, a3, 0, 0, 0);
        }

        // gates fully in-register: acc[rr] = gate rr of this lane's cell
        float gi = (a0[0] + a1[0]) + (a2[0] + a3[0]) + bv[0] + bf2f(xv.x);
        float gf = (a0[1] + a1[1]) + (a2[1] + a3[1]) + bv[1] + bf2f(xv.y);
        float gg = (a0[2] + a1[2]) + (a2[2] + a3[2]) + bv[2] + bf2f(xv.z);
        float go = (a0[3] + a1[3]) + (a2[3] + a3[3]) + bv[3] + bf2f(xv.w);
        float si = sigmoid_fast(gi), sf = sigmoid_fast(gf), so = sigmoid_fast(go);
        cstate = sf * cstate + si * tanh_fast(gg);
        float h = so * tanh_fast(cstate);

        hstage[b * 16 + ul] = __float2bfloat16(h);
        obuf[ttime & 15][tid] = h;
        __syncthreads();

        // wave 0: contiguous 1 KiB coherent h store (64 x 16B, consecutive
        // lines) -> drain -> relaxed flag post
        if (w == 0) {
            f32x4 hv = *(const f32x4*)&hstage[lane * 8];
            bf16* dst = hb_dir + (long)((t + 1) & 1) * 16384 + s * 512 + lane * 8;
            asm volatile("global_store_dwordx4 %0, %1, off sc0 sc1"
                         :: "v"(dst), "v"(hv) : "memory");
            asm volatile("s_waitcnt vmcnt(0)" ::: "memory");
            if (lane == 0)
                __hip_atomic_store(myflag, (unsigned int)(t + 1), __ATOMIC_RELAXED,
                                   __HIP_MEMORY_SCOPE_AGENT);
        }

        // output flush every 16 steps — after flag post, off the critical path
        if ((t & 15) == 15) {
            int tb = ttime & ~15;
            float vals[16];
#pragma unroll
            for (int c = 0; c < 16; ++c) vals[c] = obuf[c][tid];
            float* op = outrow + tb;
#pragma unroll
            for (int c4 = 0; c4 < 4; ++c4)
                *(f32x4*)(op + c4 * 4) = *(f32x4*)&vals[c4 * 4];
        }
    }
}

extern "C" void kernel_launch(void* const* d_in, const int* in_sizes, int n_in,
                              void* d_out, int out_size, void* d_ws, size_t ws_size,
                              hipStream_t stream) {
    const float* x     = (const float*)d_in[0];
    const float* Wih_f = (const float*)d_in[1];
    const float* Whh_f = (const float*)d_in[2];
    const float* bih_f = (const float*)d_in[3];
    const float* bhh_f = (const float*)d_in[4];
    const float* Wih_b = (const float*)d_in[5];
    const float* Whh_b = (const float*)d_in[6];
    const float* bih_b = (const float*)d_in[7];
    const float* bhh_b = (const float*)d_in[8];
    float* out = (float*)d_out;

    if (ws_size < WS_REQUIRED) {
        ws_too_small_kernel<<<1, 64, 0, stream>>>(out);
        return;
    }

    char* ws = (char*)d_ws;
    bf16* XS2  = (bf16*)(ws + OFF_XS2);
    bf16* Wcat = (bf16*)(ws + OFF_WCAT);
    bf16* Whhp = (bf16*)(ws + OFF_WHHP);
    float* bias = (float*)(ws + OFF_BIAS);
    bf16* hbuf = (bf16*)(ws + OFF_HBUF);
    unsigned int* ctr   = (unsigned int*)(ws + OFF_CTR);
    unsigned int* flags = (unsigned int*)(ws + OFF_FLAG);
    bf16* XP   = (bf16*)(ws + OFF_XP);

    pack_x_kernel<<<2048, 256, 0, stream>>>(x, XS2);
    pack_w_kernel<<<2201, 256, 0, stream>>>(Wih_f, Whh_f, bih_f, bhh_f,
                                            Wih_b, Whh_b, bih_b, bhh_b,
                                            Wcat, Whhp, bias, (unsigned int*)hbuf, ctr, flags);
    gemm_xp_kernel<<<4096, 256, 0, stream>>>(Wcat, XS2, XP);
    lstm_rec_kernel<<<64, 512, 0, stream>>>(Whhp, XP, bias, hbuf, out, flags);
}